// Round 16
// baseline (128.451 us; speedup 1.0000x reference)
//
#include <hip/hip_runtime.h>
#include <hip/hip_bf16.h>
#include <hip/hip_fp16.h>

#define DD 32
#define HH 32
#define WW 32
#define NN 32768
#define BB 2
#define CF 256
#define CC 21
#define FD 64
#define KK 19

typedef __attribute__((ext_vector_type(8))) short bf16x8;
typedef __attribute__((ext_vector_type(4))) float f32x4;

// 19 stencil offsets with |dx|+|dy|+|dz| <= 2 (order irrelevant: softmax+sum over k)
__device__ const int OFF[19][3] = {
    {-1,-1, 0}, {-1, 0,-1}, {-1, 0, 0}, {-1, 0, 1}, {-1, 1, 0},
    { 0,-1,-1}, { 0,-1, 0}, { 0,-1, 1}, { 0, 0,-1}, { 0, 0, 0},
    { 0, 0, 1}, { 0, 1,-1}, { 0, 1, 0}, { 0, 1, 1},
    { 1,-1, 0}, { 1, 0,-1}, { 1, 0, 0}, { 1, 0, 1}, { 1, 1, 0}
};

__device__ __forceinline__ unsigned short f2bf(float x) {
    unsigned u = __float_as_uint(x);
    u += 0x7FFFu + ((u >> 16) & 1u);       // round-to-nearest-even
    return (unsigned short)(u >> 16);
}

// ---------------- Kernel A: geo tables + weight prepack -------------------
// pe separable -> geo dot = 9 pairwise 32x32 tables + U/V vectors + S0.
// blocks 0-8: one T table each; block 9: U/V/S0; blocks 10-25: proj wprep
// (flat [k/8][col] fragment layout, plain RNE bf16).
__global__ __launch_bounds__(256) void tbl_kernel(
    const float* __restrict__ gtw, const float* __restrict__ gtb,
    const float* __restrict__ gpw, const float* __restrict__ gpb,
    const float* __restrict__ thw, const float* __restrict__ phw,
    float* __restrict__ Tg, uint4* __restrict__ whi)
{
    int blk = blockIdx.x, tid = threadIdx.x;
    if (blk >= 10) {
        int gid = (blk - 10) * 256 + tid;
        int col = gid & 127;
        int g8 = gid >> 7;                          // k/8, 0..31
        const float* src = (col < 64) ? (thw + col) : (phw + (col - 64));
        int kbase = g8 * 8;
        unsigned hi4[4];
#pragma unroll
        for (int e2 = 0; e2 < 4; ++e2) {
            float va = src[(kbase + 2 * e2) * 64];
            float vb = src[(kbase + 2 * e2 + 1) * 64];
            hi4[e2] = (unsigned)f2bf(va) | ((unsigned)f2bf(vb) << 16);
        }
        whi[g8 * 128 + col] = make_uint4(hi4[0], hi4[1], hi4[2], hi4[3]);
        return;
    }

    __shared__ float pe_s[32][16];        // [coord][q]: sin/cos table, once
    for (int i = tid; i < 512; i += 256) {
        int c = i >> 4, q = i & 15;
        int ii = q >> 1;
        float div = expf(-9.210340371976184f * (float)ii * 0.125f);  // (1e-4)^(ii/8)
        float ang = (float)c * div;
        pe_s[c][q] = (q & 1) ? cosf(ang) : sinf(ang);
    }
    __syncthreads();

    __shared__ float panels[6][32][65];   // [65]: conflict-free column reads
    int npan = (blk == 9) ? 6 : 2;
#pragma unroll 1
    for (int pp = 0; pp < npan; ++pp) {
        int axis, isP;
        if (blk == 9) { axis = pp % 3; isP = pp / 3; }
        else          { axis = (pp == 0) ? (blk / 3) : (blk % 3); isP = pp; }
        const float* W = isP ? gpw : gtw;
#pragma unroll
        for (int e = 0; e < 8; ++e) {
            int idx = e * 256 + tid;       // 2048 entries
            int c = idx >> 6, j = idx & 63;
            float acc = 0.f;
#pragma unroll
            for (int q = 0; q < 16; ++q)
                acc = fmaf(pe_s[c][q], W[(axis * 16 + q) * 64 + j], acc);
            panels[pp][c][j] = acc;
        }
    }
    __syncthreads();

    if (blk < 9) {
        bool tr = (blk == 6) || (blk == 7);   // T_wd, T_wh transposed
#pragma unroll
        for (int e = 0; e < 4; ++e) {
            int idx = e * 256 + tid;          // 1024 entries
            int x = idx >> 5, y = idx & 31;
            float s = 0.f;
#pragma unroll
            for (int j = 0; j < 64; ++j)
                s = fmaf(panels[0][x][j], panels[1][y][j], s);
            Tg[blk * 1024 + (tr ? (y * 32 + x) : (x * 32 + y))] = s;
        }
    } else {
        if (tid < 96) {
            int ax = tid >> 5, c = tid & 31;
            float s = 0.f;
#pragma unroll
            for (int j = 0; j < 64; ++j) s = fmaf(panels[ax][c][j], gpb[j], s);
            Tg[9216 + ax * 32 + c] = s;
        } else if (tid < 192) {
            int t2 = tid - 96;
            int ax = t2 >> 5, c = t2 & 31;
            float s = 0.f;
#pragma unroll
            for (int j = 0; j < 64; ++j) s = fmaf(gtb[j], panels[3 + ax][c][j], s);
            Tg[9312 + ax * 32 + c] = s;
        } else if (tid == 192) {
            float s = 0.f;
#pragma unroll
            for (int j = 0; j < 64; ++j) s = fmaf(gtb[j], gpb[j], s);
            Tg[9408] = s;
        }
    }
}

// ---------------- Kernel 1: projection GEMM, pure bf16 MFMA ----------------
// 64x128 tile, 4 waves (each 32x64), BK=64, grid 1024 -> 4 blocks/CU,
// LDS 24 KB. Single MFMA per fragment pair. slot = kb ^ (row&7).
__global__ __launch_bounds__(256) void proj_kernel(
    const float* __restrict__ f, const uint4* __restrict__ whi,
    const float* __restrict__ thb, const float* __restrict__ phb,
    __half* __restrict__ theta, __half* __restrict__ phi)
{
    __shared__ __align__(16) unsigned short Ahi[64][8][8];    // 8 KB
    __shared__ __align__(16) unsigned short Bhi[128][8][8];   // 16 KB

    int tid = threadIdx.x;
    int b = blockIdx.x >> 9;                  // 512 tiles per batch
    int n0 = (blockIdx.x & 511) * 64;
    int wv = tid >> 6, lane = tid & 63;
    int wr = (wv & 1) * 32, wc = (wv >> 1) * 64;
    int fr = lane & 15, kb_r = lane >> 4;

    int arow = tid & 63;                      // A staging row
    int akb0 = (tid >> 6) * 2;                // A kb base: 0,2,4,6
    int bcol = tid & 127;                     // B staging col
    int bkb0 = (tid >> 7) * 4;                // B kb base: 0 or 4

    const float* fb = f + (size_t)b * CF * NN + n0;

    f32x4 acc[2][4];
#pragma unroll
    for (int mi = 0; mi < 2; ++mi)
#pragma unroll
        for (int ni = 0; ni < 4; ++ni) acc[mi][ni] = (f32x4){0.f, 0.f, 0.f, 0.f};

#pragma unroll 1
    for (int k0 = 0; k0 < CF; k0 += 64) {
        // ---- stage A: 64 rows x 64 k; thread owns n=arow, kb=akb0..akb0+1
#pragma unroll
        for (int i = 0; i < 2; ++i) {
            int kb = akb0 + i;
            const float* src = fb + (size_t)(k0 + kb * 8) * NN + arow;
            unsigned hi4[4];
#pragma unroll
            for (int e2 = 0; e2 < 4; ++e2) {
                float va = src[(size_t)(2 * e2) * NN];
                float vb = src[(size_t)(2 * e2 + 1) * NN];
                hi4[e2] = (unsigned)f2bf(va) | ((unsigned)f2bf(vb) << 16);
            }
            int slot = kb ^ (arow & 7);
            *(uint4*)&Ahi[arow][slot][0] = make_uint4(hi4[0], hi4[1], hi4[2], hi4[3]);
        }
        // ---- stage B: prepacked fragments, straight 16B copies
        {
            const uint4* wh = whi + (size_t)(k0 >> 3) * 128;   // flat [k/8][col]
#pragma unroll
            for (int i = 0; i < 4; ++i) {
                int kb = bkb0 + i;
                uint4 hh = wh[kb * 128 + bcol];
                int slot = kb ^ (bcol & 7);
                *(uint4*)&Bhi[bcol][slot][0] = hh;
            }
        }
        __syncthreads();
        // ---- two K=32 MFMA chunks
#pragma unroll
        for (int c = 0; c < 2; ++c) {
            bf16x8 ah[2], bh[4];
            int kb_c = c * 4 + kb_r;
#pragma unroll
            for (int mi = 0; mi < 2; ++mi) {
                int r = wr + mi * 16 + fr;
                int slot = kb_c ^ (r & 7);
                ah[mi] = *(const bf16x8*)&Ahi[r][slot][0];
            }
#pragma unroll
            for (int ni = 0; ni < 4; ++ni) {
                int col = wc + ni * 16 + fr;
                int slot = kb_c ^ (col & 7);
                bh[ni] = *(const bf16x8*)&Bhi[col][slot][0];
            }
#pragma unroll
            for (int mi = 0; mi < 2; ++mi)
#pragma unroll
                for (int ni = 0; ni < 4; ++ni)
                    acc[mi][ni] = __builtin_amdgcn_mfma_f32_16x16x32_bf16(ah[mi], bh[ni], acc[mi][ni], 0, 0, 0);
        }
        __syncthreads();
    }

    // ---- epilogue: C/D col=lane&15, row=(lane>>4)*4+r; branch wave-uniform
#pragma unroll
    for (int ni = 0; ni < 4; ++ni) {
        int j = wc + ni * 16 + fr;
        float bj = (j < 64) ? thb[j] : phb[j - 64];
        __half* outp = (j < 64) ? (theta + (size_t)b * NN * 64 + j)
                                : (phi + (size_t)b * NN * 64 + (j - 64));
#pragma unroll
        for (int mi = 0; mi < 2; ++mi) {
            int nbase = n0 + wr + mi * 16 + kb_r * 4;
#pragma unroll
            for (int r = 0; r < 4; ++r)
                outp[(size_t)(nbase + r) * 64] = __float2half(acc[mi][ni][r] + bj);
        }
    }
}

// ---------------- Kernel 2: geo scores from tables ------------------------
__global__ __launch_bounds__(256) void gsc_kernel(
    const float* __restrict__ Tg, float* __restrict__ gsc)
{
    __shared__ float Ts[9 * 1024];
    __shared__ float UVs[193];
    int tid = threadIdx.x;
#pragma unroll
    for (int i = 0; i < 9; ++i) {
        int idx = i * 1024 + tid;
        Ts[idx] = Tg[idx];
        Ts[idx + 256] = Tg[idx + 256];
        Ts[idx + 512] = Tg[idx + 512];
        Ts[idx + 768] = Tg[idx + 768];
    }
    if (tid < 193) UVs[tid] = Tg[9216 + tid];
    __syncthreads();

    int n = blockIdx.x * 256 + tid;
    int d = n >> 10, h = (n >> 5) & 31, w = n & 31;
    float Un = UVs[d] + UVs[32 + h] + UVs[64 + w] + UVs[192];
    const float rs = 0.2294157338705618f;  // 1/sqrt(19)

#pragma unroll
    for (int k = 0; k < KK; ++k) {
        int nd = d + OFF[k][0], nh = h + OFF[k][1], nw = w + OFF[k][2];
        bool valid = ((unsigned)nd < 32u) && ((unsigned)nh < 32u) && ((unsigned)nw < 32u);
        int ndc = min(max(nd, 0), 31), nhc = min(max(nh, 0), 31), nwc = min(max(nw, 0), 31);
        float g = Ts[0 * 1024 + d * 32 + ndc] + Ts[1 * 1024 + d * 32 + nhc]
                + Ts[2 * 1024 + d * 32 + nwc] + Ts[3 * 1024 + h * 32 + ndc]
                + Ts[4 * 1024 + h * 32 + nhc] + Ts[5 * 1024 + h * 32 + nwc]
                + Ts[6 * 1024 + ndc * 32 + w] + Ts[7 * 1024 + nhc * 32 + w]
                + Ts[8 * 1024 + w * 32 + nwc]
                + Un + UVs[96 + ndc] + UVs[128 + nhc] + UVs[160 + nwc];
        gsc[(size_t)k * NN + n] = valid ? g * rs : -INFINITY;
    }
}

// ---------------- Kernel 3: scores + masked softmax ----------------
__global__ __launch_bounds__(256) void score_kernel(
    const __half* __restrict__ theta, const __half* __restrict__ phi,
    const float* __restrict__ gsc, float* __restrict__ wgt)
{
    int tid = threadIdx.x;
    int lane = tid & 63;
    int wv = tid >> 6;
    int sub = lane >> 4;
    int col4 = lane & 15;
    int gn = blockIdx.x * 16 + wv * 4 + sub;    // over B*N
    int b = gn >> 15;
    int n = gn & (NN - 1);
    int d = n >> 10, h = (n >> 5) & 31, w = n & 31;

    uint2 traw = *(const uint2*)(theta + (size_t)gn * 64 + col4 * 4);
    __half2 t01 = __builtin_bit_cast(__half2, traw.x);
    __half2 t23 = __builtin_bit_cast(__half2, traw.y);
    float2 tf01 = __half22float2(t01), tf23 = __half22float2(t23);
    float4 tq = {tf01.x, tf01.y, tf23.x, tf23.y};

    const __half* pb = phi + (size_t)b * NN * 64;
    const float* gr = gsc + n;
    const float rs = 0.2294157338705618f;  // 1/sqrt(19)

    float s[KK];
#pragma unroll
    for (int k = 0; k < KK; ++k) {
        int nd = d + OFF[k][0], nh = h + OFF[k][1], nw = w + OFF[k][2];
        nd = min(max(nd, 0), 31); nh = min(max(nh, 0), 31); nw = min(max(nw, 0), 31);
        int nn = (nd << 10) + (nh << 5) + nw;
        uint2 raw = *(const uint2*)(pb + (size_t)nn * 64 + col4 * 4);
        __half2 h01 = __builtin_bit_cast(__half2, raw.x);
        __half2 h23 = __builtin_bit_cast(__half2, raw.y);
        float2 f01 = __half22float2(h01), f23 = __half22float2(h23);
        float part = tq.x * f01.x + tq.y * f01.y + tq.z * f23.x + tq.w * f23.y;
        part += __shfl_xor(part, 1, 16);
        part += __shfl_xor(part, 2, 16);
        part += __shfl_xor(part, 4, 16);
        part += __shfl_xor(part, 8, 16);
        s[k] = fmaf(part, rs, gr[(size_t)k * NN]);  // gsc carries mask + scale
    }
    float m = s[0];
#pragma unroll
    for (int k = 1; k < KK; ++k) m = fmaxf(m, s[k]);
    float sum = 0.f;
#pragma unroll
    for (int k = 0; k < KK; ++k) { s[k] = __expf(s[k] - m); sum += s[k]; }
    float inv = 1.f / sum;
#pragma unroll
    for (int kk2 = 0; kk2 < 2; ++kk2) {
        int k = kk2 * 16 + col4;
        if (k < KK) wgt[((size_t)b * KK + k) * NN + n] = s[k] * inv;
    }
}

// ---------------- Kernel 4: fused double propagation ------------------------
// block = (b, 4x8x8 tile). Weights staged ONCE (k-major, coalesced) into
// Wlds[19][600] covering the 6x10x10 halo; amortized over 21 channels and
// both stencil passes. Bit-identical sums vs the two-pass version (clamped
// OOB positions annihilated by w==0).
__global__ __launch_bounds__(256) void prop2_kernel(
    const float* __restrict__ cam, const float* __restrict__ wgt,
    float* __restrict__ cout)
{
    __shared__ float Wlds[KK][600];       // 45.6 KB
    __shared__ float camt[8 * 12 * 12];   // 4.6 KB
    __shared__ float inter[6 * 10 * 10];  // 2.4 KB
    int blk = blockIdx.x;
    int tile = blk & 127;
    int b = blk >> 7;
    int tw = tile & 3, th = (tile >> 2) & 3, td = tile >> 4;
    int d0 = td * 4, h0 = th * 8, w0 = tw * 8;
    int tid = threadIdx.x;

    // ---- stage weights for the 6x10x10 halo, k-major (coalesced 10-runs)
    const float* wb = wgt + (size_t)b * KK * NN;
    for (int i = tid; i < 600 * KK; i += 256) {
        int k = i / 600, j = i - k * 600;
        int lw = j % 10, lh = (j / 10) % 10, ld = j / 100;
        int gd = min(max(d0 - 1 + ld, 0), 31);
        int gh = min(max(h0 - 1 + lh, 0), 31);
        int gw = min(max(w0 - 1 + lw, 0), 31);
        Wlds[k][j] = wb[(size_t)k * NN + (gd << 10) + (gh << 5) + gw];
    }

    int flw = tid & 7, flh = (tid >> 3) & 7, fld = tid >> 6;  // final out node
    int fj = (fld + 1) * 100 + (flh + 1) * 10 + (flw + 1);
    int fn = ((d0 + fld) << 10) + ((h0 + flh) << 5) + (w0 + flw);

#pragma unroll 1
    for (int c = 0; c < CC; ++c) {
        const float* cb = cam + ((size_t)b * CC + c) * NN;
        // stage cam halo (clamped); safe: prior channel's camt readers are
        // all past the inter-phase barrier.
        for (int i = tid; i < 1152; i += 256) {
            int lw = i % 12, lh = (i / 12) % 12, ld = i / 144;
            int gd = min(max(d0 - 2 + ld, 0), 31);
            int gh = min(max(h0 - 2 + lh, 0), 31);
            int gw = min(max(w0 - 2 + lw, 0), 31);
            camt[i] = cb[(gd << 10) + (gh << 5) + gw];
        }
        __syncthreads();                       // camt (+ Wlds, first iter) ready
        // pass 1: intermediate on the 6x10x10 halo
        for (int i = tid; i < 600; i += 256) {
            int lw = i % 10, lh = (i / 10) % 10, ld = i / 100;
            int cbase = (ld + 1) * 144 + (lh + 1) * 12 + (lw + 1);
            float acc = 0.f;
#pragma unroll
            for (int k = 0; k < KK; ++k)
                acc = fmaf(Wlds[k][i], camt[cbase + OFF[k][0] * 144 + OFF[k][1] * 12 + OFF[k][2]], acc);
            inter[i] = acc;
        }
        __syncthreads();                       // inter ready
        // pass 2: final 256 outputs
        {
            float acc = 0.f;
#pragma unroll
            for (int k = 0; k < KK; ++k)
                acc = fmaf(Wlds[k][fj], inter[fj + OFF[k][0] * 100 + OFF[k][1] * 10 + OFF[k][2]], acc);
            cout[((size_t)b * CC + c) * NN + fn] = acc;
        }
    }
}

extern "C" void kernel_launch(void* const* d_in, const int* in_sizes, int n_in,
                              void* d_out, int out_size, void* d_ws, size_t ws_size,
                              hipStream_t stream) {
    const float* cam = (const float*)d_in[0];
    const float* f   = (const float*)d_in[1];
    const float* thw = (const float*)d_in[2];
    const float* thb = (const float*)d_in[3];
    const float* phw = (const float*)d_in[4];
    const float* phb = (const float*)d_in[5];
    const float* gtw = (const float*)d_in[6];
    const float* gtb = (const float*)d_in[7];
    const float* gpw = (const float*)d_in[8];
    const float* gpb = (const float*)d_in[9];

    float*  ws    = (float*)d_ws;
    __half* theta = (__half*)ws;                                  // [B,N,64] f16
    __half* phi   = theta + (size_t)BB * NN * 64;                 // [B,N,64] f16
    float*  wgt   = (float*)(phi + (size_t)BB * NN * 64);         // [B,19,N] f32
    float*  gsc   = wgt + (size_t)BB * KK * NN;                   // [19,N] k-major
    uint4*  whi   = (uint4*)(gsc + (size_t)KK * NN);              // 4096 uint4
    float*  Tg    = (float*)(whi + 4096);                         // 9409 floats

    tbl_kernel<<<26, 256, 0, stream>>>(gtw, gtb, gpw, gpb, thw, phw, Tg, whi);
    proj_kernel<<<1024, 256, 0, stream>>>(f, whi, thb, phb, theta, phi);
    gsc_kernel<<<NN / 256, 256, 0, stream>>>(Tg, gsc);
    score_kernel<<<BB * NN / 16, 256, 0, stream>>>(theta, phi, gsc, wgt);
    prop2_kernel<<<BB * 128, 256, 0, stream>>>(cam, wgt, (float*)d_out);
}

// Round 17
// 71.481 us; speedup vs baseline: 1.7970x; 1.7970x over previous
//
#include <hip/hip_runtime.h>
#include <hip/hip_bf16.h>
#include <hip/hip_fp16.h>

#define DD 32
#define HH 32
#define WW 32
#define NN 32768
#define BB 2
#define CF 256
#define CC 21
#define FD 64
#define KK 19

typedef __attribute__((ext_vector_type(8))) short bf16x8;
typedef __attribute__((ext_vector_type(4))) float f32x4;

// 19 stencil offsets with |dx|+|dy|+|dz| <= 2 (order irrelevant: softmax+sum over k)
__device__ const int OFF[19][3] = {
    {-1,-1, 0}, {-1, 0,-1}, {-1, 0, 0}, {-1, 0, 1}, {-1, 1, 0},
    { 0,-1,-1}, { 0,-1, 0}, { 0,-1, 1}, { 0, 0,-1}, { 0, 0, 0},
    { 0, 0, 1}, { 0, 1,-1}, { 0, 1, 0}, { 0, 1, 1},
    { 1,-1, 0}, { 1, 0,-1}, { 1, 0, 0}, { 1, 0, 1}, { 1, 1, 0}
};

__device__ __forceinline__ unsigned short f2bf(float x) {
    unsigned u = __float_as_uint(x);
    u += 0x7FFFu + ((u >> 16) & 1u);       // round-to-nearest-even
    return (unsigned short)(u >> 16);
}

// ---------------- Kernel A: geo tables + weight prepack -------------------
// pe separable -> geo dot = 9 pairwise 32x32 tables + U/V vectors + S0.
// blocks 0-8: one T table each; block 9: U/V/S0; blocks 10-25: proj wprep
// (flat [k/8][col] fragment layout, plain RNE bf16).
__global__ __launch_bounds__(256) void tbl_kernel(
    const float* __restrict__ gtw, const float* __restrict__ gtb,
    const float* __restrict__ gpw, const float* __restrict__ gpb,
    const float* __restrict__ thw, const float* __restrict__ phw,
    float* __restrict__ Tg, uint4* __restrict__ whi)
{
    int blk = blockIdx.x, tid = threadIdx.x;
    if (blk >= 10) {
        int gid = (blk - 10) * 256 + tid;
        int col = gid & 127;
        int g8 = gid >> 7;                          // k/8, 0..31
        const float* src = (col < 64) ? (thw + col) : (phw + (col - 64));
        int kbase = g8 * 8;
        unsigned hi4[4];
#pragma unroll
        for (int e2 = 0; e2 < 4; ++e2) {
            float va = src[(kbase + 2 * e2) * 64];
            float vb = src[(kbase + 2 * e2 + 1) * 64];
            hi4[e2] = (unsigned)f2bf(va) | ((unsigned)f2bf(vb) << 16);
        }
        whi[g8 * 128 + col] = make_uint4(hi4[0], hi4[1], hi4[2], hi4[3]);
        return;
    }

    __shared__ float pe_s[32][16];        // [coord][q]: sin/cos table, once
    for (int i = tid; i < 512; i += 256) {
        int c = i >> 4, q = i & 15;
        int ii = q >> 1;
        float div = expf(-9.210340371976184f * (float)ii * 0.125f);  // (1e-4)^(ii/8)
        float ang = (float)c * div;
        pe_s[c][q] = (q & 1) ? cosf(ang) : sinf(ang);
    }
    __syncthreads();

    __shared__ float panels[6][32][65];   // [65]: conflict-free column reads
    int npan = (blk == 9) ? 6 : 2;
#pragma unroll 1
    for (int pp = 0; pp < npan; ++pp) {
        int axis, isP;
        if (blk == 9) { axis = pp % 3; isP = pp / 3; }
        else          { axis = (pp == 0) ? (blk / 3) : (blk % 3); isP = pp; }
        const float* W = isP ? gpw : gtw;
#pragma unroll
        for (int e = 0; e < 8; ++e) {
            int idx = e * 256 + tid;       // 2048 entries
            int c = idx >> 6, j = idx & 63;
            float acc = 0.f;
#pragma unroll
            for (int q = 0; q < 16; ++q)
                acc = fmaf(pe_s[c][q], W[(axis * 16 + q) * 64 + j], acc);
            panels[pp][c][j] = acc;
        }
    }
    __syncthreads();

    if (blk < 9) {
        bool tr = (blk == 6) || (blk == 7);   // T_wd, T_wh transposed
#pragma unroll
        for (int e = 0; e < 4; ++e) {
            int idx = e * 256 + tid;          // 1024 entries
            int x = idx >> 5, y = idx & 31;
            float s = 0.f;
#pragma unroll
            for (int j = 0; j < 64; ++j)
                s = fmaf(panels[0][x][j], panels[1][y][j], s);
            Tg[blk * 1024 + (tr ? (y * 32 + x) : (x * 32 + y))] = s;
        }
    } else {
        if (tid < 96) {
            int ax = tid >> 5, c = tid & 31;
            float s = 0.f;
#pragma unroll
            for (int j = 0; j < 64; ++j) s = fmaf(panels[ax][c][j], gpb[j], s);
            Tg[9216 + ax * 32 + c] = s;
        } else if (tid < 192) {
            int t2 = tid - 96;
            int ax = t2 >> 5, c = t2 & 31;
            float s = 0.f;
#pragma unroll
            for (int j = 0; j < 64; ++j) s = fmaf(gtb[j], panels[3 + ax][c][j], s);
            Tg[9312 + ax * 32 + c] = s;
        } else if (tid == 192) {
            float s = 0.f;
#pragma unroll
            for (int j = 0; j < 64; ++j) s = fmaf(gtb[j], gpb[j], s);
            Tg[9408] = s;
        }
    }
}

// ---------------- Kernel 1: projection GEMM, pure bf16 MFMA ----------------
// 64x128 tile, 4 waves (each 32x64), BK=64, grid 1024 -> 4 blocks/CU,
// LDS 24 KB. Single MFMA per fragment pair. slot = kb ^ (row&7).
__global__ __launch_bounds__(256) void proj_kernel(
    const float* __restrict__ f, const uint4* __restrict__ whi,
    const float* __restrict__ thb, const float* __restrict__ phb,
    __half* __restrict__ theta, __half* __restrict__ phi)
{
    __shared__ __align__(16) unsigned short Ahi[64][8][8];    // 8 KB
    __shared__ __align__(16) unsigned short Bhi[128][8][8];   // 16 KB

    int tid = threadIdx.x;
    int b = blockIdx.x >> 9;                  // 512 tiles per batch
    int n0 = (blockIdx.x & 511) * 64;
    int wv = tid >> 6, lane = tid & 63;
    int wr = (wv & 1) * 32, wc = (wv >> 1) * 64;
    int fr = lane & 15, kb_r = lane >> 4;

    int arow = tid & 63;                      // A staging row
    int akb0 = (tid >> 6) * 2;                // A kb base: 0,2,4,6
    int bcol = tid & 127;                     // B staging col
    int bkb0 = (tid >> 7) * 4;                // B kb base: 0 or 4

    const float* fb = f + (size_t)b * CF * NN + n0;

    f32x4 acc[2][4];
#pragma unroll
    for (int mi = 0; mi < 2; ++mi)
#pragma unroll
        for (int ni = 0; ni < 4; ++ni) acc[mi][ni] = (f32x4){0.f, 0.f, 0.f, 0.f};

#pragma unroll 1
    for (int k0 = 0; k0 < CF; k0 += 64) {
        // ---- stage A: 64 rows x 64 k; thread owns n=arow, kb=akb0..akb0+1
#pragma unroll
        for (int i = 0; i < 2; ++i) {
            int kb = akb0 + i;
            const float* src = fb + (size_t)(k0 + kb * 8) * NN + arow;
            unsigned hi4[4];
#pragma unroll
            for (int e2 = 0; e2 < 4; ++e2) {
                float va = src[(size_t)(2 * e2) * NN];
                float vb = src[(size_t)(2 * e2 + 1) * NN];
                hi4[e2] = (unsigned)f2bf(va) | ((unsigned)f2bf(vb) << 16);
            }
            int slot = kb ^ (arow & 7);
            *(uint4*)&Ahi[arow][slot][0] = make_uint4(hi4[0], hi4[1], hi4[2], hi4[3]);
        }
        // ---- stage B: prepacked fragments, straight 16B copies
        {
            const uint4* wh = whi + (size_t)(k0 >> 3) * 128;   // flat [k/8][col]
#pragma unroll
            for (int i = 0; i < 4; ++i) {
                int kb = bkb0 + i;
                uint4 hh = wh[kb * 128 + bcol];
                int slot = kb ^ (bcol & 7);
                *(uint4*)&Bhi[bcol][slot][0] = hh;
            }
        }
        __syncthreads();
        // ---- two K=32 MFMA chunks
#pragma unroll
        for (int c = 0; c < 2; ++c) {
            bf16x8 ah[2], bh[4];
            int kb_c = c * 4 + kb_r;
#pragma unroll
            for (int mi = 0; mi < 2; ++mi) {
                int r = wr + mi * 16 + fr;
                int slot = kb_c ^ (r & 7);
                ah[mi] = *(const bf16x8*)&Ahi[r][slot][0];
            }
#pragma unroll
            for (int ni = 0; ni < 4; ++ni) {
                int col = wc + ni * 16 + fr;
                int slot = kb_c ^ (col & 7);
                bh[ni] = *(const bf16x8*)&Bhi[col][slot][0];
            }
#pragma unroll
            for (int mi = 0; mi < 2; ++mi)
#pragma unroll
                for (int ni = 0; ni < 4; ++ni)
                    acc[mi][ni] = __builtin_amdgcn_mfma_f32_16x16x32_bf16(ah[mi], bh[ni], acc[mi][ni], 0, 0, 0);
        }
        __syncthreads();
    }

    // ---- epilogue: C/D col=lane&15, row=(lane>>4)*4+r; branch wave-uniform
#pragma unroll
    for (int ni = 0; ni < 4; ++ni) {
        int j = wc + ni * 16 + fr;
        float bj = (j < 64) ? thb[j] : phb[j - 64];
        __half* outp = (j < 64) ? (theta + (size_t)b * NN * 64 + j)
                                : (phi + (size_t)b * NN * 64 + (j - 64));
#pragma unroll
        for (int mi = 0; mi < 2; ++mi) {
            int nbase = n0 + wr + mi * 16 + kb_r * 4;
#pragma unroll
            for (int r = 0; r < 4; ++r)
                outp[(size_t)(nbase + r) * 64] = __float2half(acc[mi][ni][r] + bj);
        }
    }
}

// ---------------- Kernel 2: geo scores from tables ------------------------
__global__ __launch_bounds__(256) void gsc_kernel(
    const float* __restrict__ Tg, float* __restrict__ gsc)
{
    __shared__ float Ts[9 * 1024];
    __shared__ float UVs[193];
    int tid = threadIdx.x;
#pragma unroll
    for (int i = 0; i < 9; ++i) {
        int idx = i * 1024 + tid;
        Ts[idx] = Tg[idx];
        Ts[idx + 256] = Tg[idx + 256];
        Ts[idx + 512] = Tg[idx + 512];
        Ts[idx + 768] = Tg[idx + 768];
    }
    if (tid < 193) UVs[tid] = Tg[9216 + tid];
    __syncthreads();

    int n = blockIdx.x * 256 + tid;
    int d = n >> 10, h = (n >> 5) & 31, w = n & 31;
    float Un = UVs[d] + UVs[32 + h] + UVs[64 + w] + UVs[192];
    const float rs = 0.2294157338705618f;  // 1/sqrt(19)

#pragma unroll
    for (int k = 0; k < KK; ++k) {
        int nd = d + OFF[k][0], nh = h + OFF[k][1], nw = w + OFF[k][2];
        bool valid = ((unsigned)nd < 32u) && ((unsigned)nh < 32u) && ((unsigned)nw < 32u);
        int ndc = min(max(nd, 0), 31), nhc = min(max(nh, 0), 31), nwc = min(max(nw, 0), 31);
        float g = Ts[0 * 1024 + d * 32 + ndc] + Ts[1 * 1024 + d * 32 + nhc]
                + Ts[2 * 1024 + d * 32 + nwc] + Ts[3 * 1024 + h * 32 + ndc]
                + Ts[4 * 1024 + h * 32 + nhc] + Ts[5 * 1024 + h * 32 + nwc]
                + Ts[6 * 1024 + ndc * 32 + w] + Ts[7 * 1024 + nhc * 32 + w]
                + Ts[8 * 1024 + w * 32 + nwc]
                + Un + UVs[96 + ndc] + UVs[128 + nhc] + UVs[160 + nwc];
        gsc[(size_t)k * NN + n] = valid ? g * rs : -INFINITY;
    }
}

// ---------------- Kernel 3: scores + masked softmax ----------------
__global__ __launch_bounds__(256) void score_kernel(
    const __half* __restrict__ theta, const __half* __restrict__ phi,
    const float* __restrict__ gsc, float* __restrict__ wgt)
{
    int tid = threadIdx.x;
    int lane = tid & 63;
    int wv = tid >> 6;
    int sub = lane >> 4;
    int col4 = lane & 15;
    int gn = blockIdx.x * 16 + wv * 4 + sub;    // over B*N
    int b = gn >> 15;
    int n = gn & (NN - 1);
    int d = n >> 10, h = (n >> 5) & 31, w = n & 31;

    uint2 traw = *(const uint2*)(theta + (size_t)gn * 64 + col4 * 4);
    __half2 t01 = __builtin_bit_cast(__half2, traw.x);
    __half2 t23 = __builtin_bit_cast(__half2, traw.y);
    float2 tf01 = __half22float2(t01), tf23 = __half22float2(t23);
    float4 tq = {tf01.x, tf01.y, tf23.x, tf23.y};

    const __half* pb = phi + (size_t)b * NN * 64;
    const float* gr = gsc + n;
    const float rs = 0.2294157338705618f;  // 1/sqrt(19)

    float s[KK];
#pragma unroll
    for (int k = 0; k < KK; ++k) {
        int nd = d + OFF[k][0], nh = h + OFF[k][1], nw = w + OFF[k][2];
        nd = min(max(nd, 0), 31); nh = min(max(nh, 0), 31); nw = min(max(nw, 0), 31);
        int nn = (nd << 10) + (nh << 5) + nw;
        uint2 raw = *(const uint2*)(pb + (size_t)nn * 64 + col4 * 4);
        __half2 h01 = __builtin_bit_cast(__half2, raw.x);
        __half2 h23 = __builtin_bit_cast(__half2, raw.y);
        float2 f01 = __half22float2(h01), f23 = __half22float2(h23);
        float part = tq.x * f01.x + tq.y * f01.y + tq.z * f23.x + tq.w * f23.y;
        part += __shfl_xor(part, 1, 16);
        part += __shfl_xor(part, 2, 16);
        part += __shfl_xor(part, 4, 16);
        part += __shfl_xor(part, 8, 16);
        s[k] = fmaf(part, rs, gr[(size_t)k * NN]);  // gsc carries mask + scale
    }
    float m = s[0];
#pragma unroll
    for (int k = 1; k < KK; ++k) m = fmaxf(m, s[k]);
    float sum = 0.f;
#pragma unroll
    for (int k = 0; k < KK; ++k) { s[k] = __expf(s[k] - m); sum += s[k]; }
    float inv = 1.f / sum;
#pragma unroll
    for (int kk2 = 0; kk2 < 2; ++kk2) {
        int k = kk2 * 16 + col4;
        if (k < KK) wgt[((size_t)b * KK + k) * NN + n] = s[k] * inv;
    }
}

// ---------------- Kernel 4: propagation, wgt hoisted across channels -------
// thread = (b, n, c-group of 7); loads 19 weights + 19 neighbor idx ONCE,
// loops 7 channels. 768 blocks -> 12 waves/CU. (round-12/13 measured-good)
__global__ __launch_bounds__(256) void prop_kernel(
    const float* __restrict__ cin, const float* __restrict__ wgt,
    float* __restrict__ cout)
{
    int gid = blockIdx.x * 256 + threadIdx.x;   // B*N*3 threads
    int n = gid & (NN - 1);
    int rest = gid >> 15;                       // 0..5
    int b = rest / 3, cg = rest % 3;
    int c0 = cg * 7;
    int d = n >> 10, h = (n >> 5) & 31, w = n & 31;

    const float* wb = wgt + (size_t)b * KK * NN + n;
    int nidx[KK];
    float wv[KK];
#pragma unroll
    for (int k = 0; k < KK; ++k) {
        int nd = d + OFF[k][0], nh = h + OFF[k][1], nw = w + OFF[k][2];
        nd = min(max(nd, 0), 31); nh = min(max(nh, 0), 31); nw = min(max(nw, 0), 31);
        nidx[k] = (nd << 10) + (nh << 5) + nw;
        wv[k] = wb[(size_t)k * NN];
    }

    const float* cb = cin + ((size_t)b * CC + c0) * NN;
    float* co = cout + ((size_t)b * CC + c0) * NN + n;
#pragma unroll
    for (int cc = 0; cc < 7; ++cc) {
        float acc = 0.f;
#pragma unroll
        for (int k = 0; k < KK; ++k)
            acc = fmaf(wv[k], cb[nidx[k]], acc);
        co[(size_t)cc * NN] = acc;
        cb += NN;
    }
}

extern "C" void kernel_launch(void* const* d_in, const int* in_sizes, int n_in,
                              void* d_out, int out_size, void* d_ws, size_t ws_size,
                              hipStream_t stream) {
    const float* cam = (const float*)d_in[0];
    const float* f   = (const float*)d_in[1];
    const float* thw = (const float*)d_in[2];
    const float* thb = (const float*)d_in[3];
    const float* phw = (const float*)d_in[4];
    const float* phb = (const float*)d_in[5];
    const float* gtw = (const float*)d_in[6];
    const float* gtb = (const float*)d_in[7];
    const float* gpw = (const float*)d_in[8];
    const float* gpb = (const float*)d_in[9];

    float*  ws    = (float*)d_ws;
    __half* theta = (__half*)ws;                                  // [B,N,64] f16
    __half* phi   = theta + (size_t)BB * NN * 64;                 // [B,N,64] f16
    float*  wgt   = (float*)(phi + (size_t)BB * NN * 64);         // [B,19,N] f32
    float*  gsc   = wgt + (size_t)BB * KK * NN;                   // [19,N] k-major
    float*  cam1  = gsc + (size_t)KK * NN;                        // [B,21,N]
    uint4*  whi   = (uint4*)(cam1 + (size_t)BB * CC * NN);        // 4096 uint4
    float*  Tg    = (float*)(whi + 4096);                         // 9409 floats

    tbl_kernel<<<26, 256, 0, stream>>>(gtw, gtb, gpw, gpb, thw, phw, Tg, whi);
    proj_kernel<<<1024, 256, 0, stream>>>(f, whi, thb, phb, theta, phi);
    gsc_kernel<<<NN / 256, 256, 0, stream>>>(Tg, gsc);
    score_kernel<<<BB * NN / 16, 256, 0, stream>>>(theta, phi, gsc, wgt);
    prop_kernel<<<BB * NN * 3 / 256, 256, 0, stream>>>(cam, wgt, cam1);
    prop_kernel<<<BB * NN * 3 / 256, 256, 0, stream>>>(cam1, wgt, (float*)d_out);
}

// Round 18
// 65.485 us; speedup vs baseline: 1.9615x; 1.0916x over previous
//
#include <hip/hip_runtime.h>
#include <hip/hip_bf16.h>
#include <hip/hip_fp16.h>

#define DD 32
#define HH 32
#define WW 32
#define NN 32768
#define BB 2
#define CF 256
#define CC 21
#define FD 64
#define KK 19

typedef __attribute__((ext_vector_type(8))) short bf16x8;
typedef __attribute__((ext_vector_type(4))) float f32x4;

// 19 stencil offsets with |dx|+|dy|+|dz| <= 2 (order irrelevant: softmax+sum over k)
__device__ const int OFF[19][3] = {
    {-1,-1, 0}, {-1, 0,-1}, {-1, 0, 0}, {-1, 0, 1}, {-1, 1, 0},
    { 0,-1,-1}, { 0,-1, 0}, { 0,-1, 1}, { 0, 0,-1}, { 0, 0, 0},
    { 0, 0, 1}, { 0, 1,-1}, { 0, 1, 0}, { 0, 1, 1},
    { 1,-1, 0}, { 1, 0,-1}, { 1, 0, 0}, { 1, 0, 1}, { 1, 1, 0}
};

__device__ __forceinline__ unsigned short f2bf(float x) {
    unsigned u = __float_as_uint(x);
    u += 0x7FFFu + ((u >> 16) & 1u);       // round-to-nearest-even
    return (unsigned short)(u >> 16);
}

// ---------------- Kernel A: geo tables + weight prepack -------------------
// pe separable -> geo dot = 9 pairwise 32x32 tables + U/V vectors + S0.
// blocks 0-8: one T table each; block 9: U/V/S0; blocks 10-25: proj wprep
// (flat [k/8][col] fragment layout, plain RNE bf16).
__global__ __launch_bounds__(256) void tbl_kernel(
    const float* __restrict__ gtw, const float* __restrict__ gtb,
    const float* __restrict__ gpw, const float* __restrict__ gpb,
    const float* __restrict__ thw, const float* __restrict__ phw,
    float* __restrict__ Tg, uint4* __restrict__ whi)
{
    int blk = blockIdx.x, tid = threadIdx.x;
    if (blk >= 10) {
        int gid = (blk - 10) * 256 + tid;
        int col = gid & 127;
        int g8 = gid >> 7;                          // k/8, 0..31
        const float* src = (col < 64) ? (thw + col) : (phw + (col - 64));
        int kbase = g8 * 8;
        unsigned hi4[4];
#pragma unroll
        for (int e2 = 0; e2 < 4; ++e2) {
            float va = src[(kbase + 2 * e2) * 64];
            float vb = src[(kbase + 2 * e2 + 1) * 64];
            hi4[e2] = (unsigned)f2bf(va) | ((unsigned)f2bf(vb) << 16);
        }
        whi[g8 * 128 + col] = make_uint4(hi4[0], hi4[1], hi4[2], hi4[3]);
        return;
    }

    __shared__ float pe_s[32][16];        // [coord][q]: sin/cos table, once
    for (int i = tid; i < 512; i += 256) {
        int c = i >> 4, q = i & 15;
        int ii = q >> 1;
        float div = expf(-9.210340371976184f * (float)ii * 0.125f);  // (1e-4)^(ii/8)
        float ang = (float)c * div;
        pe_s[c][q] = (q & 1) ? cosf(ang) : sinf(ang);
    }
    __syncthreads();

    __shared__ float panels[6][32][65];   // [65]: conflict-free column reads
    int npan = (blk == 9) ? 6 : 2;
#pragma unroll 1
    for (int pp = 0; pp < npan; ++pp) {
        int axis, isP;
        if (blk == 9) { axis = pp % 3; isP = pp / 3; }
        else          { axis = (pp == 0) ? (blk / 3) : (blk % 3); isP = pp; }
        const float* W = isP ? gpw : gtw;
#pragma unroll
        for (int e = 0; e < 8; ++e) {
            int idx = e * 256 + tid;       // 2048 entries
            int c = idx >> 6, j = idx & 63;
            float acc = 0.f;
#pragma unroll
            for (int q = 0; q < 16; ++q)
                acc = fmaf(pe_s[c][q], W[(axis * 16 + q) * 64 + j], acc);
            panels[pp][c][j] = acc;
        }
    }
    __syncthreads();

    if (blk < 9) {
        bool tr = (blk == 6) || (blk == 7);   // T_wd, T_wh transposed
#pragma unroll
        for (int e = 0; e < 4; ++e) {
            int idx = e * 256 + tid;          // 1024 entries
            int x = idx >> 5, y = idx & 31;
            float s = 0.f;
#pragma unroll
            for (int j = 0; j < 64; ++j)
                s = fmaf(panels[0][x][j], panels[1][y][j], s);
            Tg[blk * 1024 + (tr ? (y * 32 + x) : (x * 32 + y))] = s;
        }
    } else {
        if (tid < 96) {
            int ax = tid >> 5, c = tid & 31;
            float s = 0.f;
#pragma unroll
            for (int j = 0; j < 64; ++j) s = fmaf(panels[ax][c][j], gpb[j], s);
            Tg[9216 + ax * 32 + c] = s;
        } else if (tid < 192) {
            int t2 = tid - 96;
            int ax = t2 >> 5, c = t2 & 31;
            float s = 0.f;
#pragma unroll
            for (int j = 0; j < 64; ++j) s = fmaf(gtb[j], panels[3 + ax][c][j], s);
            Tg[9312 + ax * 32 + c] = s;
        } else if (tid == 192) {
            float s = 0.f;
#pragma unroll
            for (int j = 0; j < 64; ++j) s = fmaf(gtb[j], gpb[j], s);
            Tg[9408] = s;
        }
    }
}

// ---------------- Kernel 1: projection GEMM, pure bf16 MFMA ----------------
// 128x128 tile, 8 waves (each 32x64 quadrant), BK=64, 4 K-steps.
// grid 512, LDS 32 KB -> 2 blocks/CU but 16 waves/CU (vs 8 at 4-wave).
// Single MFMA per fragment pair; slot = kb ^ (row&7). theta/phi f16 out.
__global__ __launch_bounds__(512) void proj_kernel(
    const float* __restrict__ f, const uint4* __restrict__ whi,
    const float* __restrict__ thb, const float* __restrict__ phb,
    __half* __restrict__ theta, __half* __restrict__ phi)
{
    __shared__ __align__(16) unsigned short Ahi[128][8][8];   // 16 KB
    __shared__ __align__(16) unsigned short Bhi[128][8][8];   // 16 KB

    int tid = threadIdx.x;
    int b = blockIdx.x >> 8;                  // 256 tiles per batch
    int n0 = (blockIdx.x & 255) * 128;
    int wv = tid >> 6, lane = tid & 63;
    int wr = (wv & 3) * 32, wc = (wv >> 2) * 64;
    int fr = lane & 15, kb_r = lane >> 4;

    int srow = tid & 127;                     // staging row (A) / col (B)
    int kb0 = (tid >> 7) * 2;                 // staging kb base: 0,2,4,6

    const float* fb = f + (size_t)b * CF * NN + n0;

    f32x4 acc[2][4];
#pragma unroll
    for (int mi = 0; mi < 2; ++mi)
#pragma unroll
        for (int ni = 0; ni < 4; ++ni) acc[mi][ni] = (f32x4){0.f, 0.f, 0.f, 0.f};

#pragma unroll 1
    for (int k0 = 0; k0 < CF; k0 += 64) {
        // ---- stage A: 128 rows x 64 k; thread owns n=srow, kb=kb0..kb0+1
#pragma unroll
        for (int i = 0; i < 2; ++i) {
            int kb = kb0 + i;
            const float* src = fb + (size_t)(k0 + kb * 8) * NN + srow;
            unsigned hi4[4];
#pragma unroll
            for (int e2 = 0; e2 < 4; ++e2) {
                float va = src[(size_t)(2 * e2) * NN];
                float vb = src[(size_t)(2 * e2 + 1) * NN];
                hi4[e2] = (unsigned)f2bf(va) | ((unsigned)f2bf(vb) << 16);
            }
            int slot = kb ^ (srow & 7);
            *(uint4*)&Ahi[srow][slot][0] = make_uint4(hi4[0], hi4[1], hi4[2], hi4[3]);
        }
        // ---- stage B: prepacked fragments, straight 16B copies
        {
            const uint4* wh = whi + (size_t)(k0 >> 3) * 128;   // flat [k/8][col]
#pragma unroll
            for (int i = 0; i < 2; ++i) {
                int kb = kb0 + i;
                uint4 hh = wh[kb * 128 + srow];
                int slot = kb ^ (srow & 7);
                *(uint4*)&Bhi[srow][slot][0] = hh;
            }
        }
        __syncthreads();
        // ---- two K=32 MFMA chunks
#pragma unroll
        for (int c = 0; c < 2; ++c) {
            bf16x8 ah[2], bh[4];
            int kb_c = c * 4 + kb_r;
#pragma unroll
            for (int mi = 0; mi < 2; ++mi) {
                int r = wr + mi * 16 + fr;
                int slot = kb_c ^ (r & 7);
                ah[mi] = *(const bf16x8*)&Ahi[r][slot][0];
            }
#pragma unroll
            for (int ni = 0; ni < 4; ++ni) {
                int col = wc + ni * 16 + fr;
                int slot = kb_c ^ (col & 7);
                bh[ni] = *(const bf16x8*)&Bhi[col][slot][0];
            }
#pragma unroll
            for (int mi = 0; mi < 2; ++mi)
#pragma unroll
                for (int ni = 0; ni < 4; ++ni)
                    acc[mi][ni] = __builtin_amdgcn_mfma_f32_16x16x32_bf16(ah[mi], bh[ni], acc[mi][ni], 0, 0, 0);
        }
        __syncthreads();
    }

    // ---- epilogue: C/D col=lane&15, row=(lane>>4)*4+r; branch wave-uniform
#pragma unroll
    for (int ni = 0; ni < 4; ++ni) {
        int j = wc + ni * 16 + fr;
        float bj = (j < 64) ? thb[j] : phb[j - 64];
        __half* outp = (j < 64) ? (theta + (size_t)b * NN * 64 + j)
                                : (phi + (size_t)b * NN * 64 + (j - 64));
#pragma unroll
        for (int mi = 0; mi < 2; ++mi) {
            int nbase = n0 + wr + mi * 16 + kb_r * 4;
#pragma unroll
            for (int r = 0; r < 4; ++r)
                outp[(size_t)(nbase + r) * 64] = __float2half(acc[mi][ni][r] + bj);
        }
    }
}

// ---------------- Kernel 2: geo scores from tables ------------------------
__global__ __launch_bounds__(256) void gsc_kernel(
    const float* __restrict__ Tg, float* __restrict__ gsc)
{
    __shared__ float Ts[9 * 1024];
    __shared__ float UVs[193];
    int tid = threadIdx.x;
#pragma unroll
    for (int i = 0; i < 9; ++i) {
        int idx = i * 1024 + tid;
        Ts[idx] = Tg[idx];
        Ts[idx + 256] = Tg[idx + 256];
        Ts[idx + 512] = Tg[idx + 512];
        Ts[idx + 768] = Tg[idx + 768];
    }
    if (tid < 193) UVs[tid] = Tg[9216 + tid];
    __syncthreads();

    int n = blockIdx.x * 256 + tid;
    int d = n >> 10, h = (n >> 5) & 31, w = n & 31;
    float Un = UVs[d] + UVs[32 + h] + UVs[64 + w] + UVs[192];
    const float rs = 0.2294157338705618f;  // 1/sqrt(19)

#pragma unroll
    for (int k = 0; k < KK; ++k) {
        int nd = d + OFF[k][0], nh = h + OFF[k][1], nw = w + OFF[k][2];
        bool valid = ((unsigned)nd < 32u) && ((unsigned)nh < 32u) && ((unsigned)nw < 32u);
        int ndc = min(max(nd, 0), 31), nhc = min(max(nh, 0), 31), nwc = min(max(nw, 0), 31);
        float g = Ts[0 * 1024 + d * 32 + ndc] + Ts[1 * 1024 + d * 32 + nhc]
                + Ts[2 * 1024 + d * 32 + nwc] + Ts[3 * 1024 + h * 32 + ndc]
                + Ts[4 * 1024 + h * 32 + nhc] + Ts[5 * 1024 + h * 32 + nwc]
                + Ts[6 * 1024 + ndc * 32 + w] + Ts[7 * 1024 + nhc * 32 + w]
                + Ts[8 * 1024 + w * 32 + nwc]
                + Un + UVs[96 + ndc] + UVs[128 + nhc] + UVs[160 + nwc];
        gsc[(size_t)k * NN + n] = valid ? g * rs : -INFINITY;
    }
}

// ---------------- Kernel 3: scores + masked softmax ----------------
__global__ __launch_bounds__(256) void score_kernel(
    const __half* __restrict__ theta, const __half* __restrict__ phi,
    const float* __restrict__ gsc, float* __restrict__ wgt)
{
    int tid = threadIdx.x;
    int lane = tid & 63;
    int wv = tid >> 6;
    int sub = lane >> 4;
    int col4 = lane & 15;
    int gn = blockIdx.x * 16 + wv * 4 + sub;    // over B*N
    int b = gn >> 15;
    int n = gn & (NN - 1);
    int d = n >> 10, h = (n >> 5) & 31, w = n & 31;

    uint2 traw = *(const uint2*)(theta + (size_t)gn * 64 + col4 * 4);
    __half2 t01 = __builtin_bit_cast(__half2, traw.x);
    __half2 t23 = __builtin_bit_cast(__half2, traw.y);
    float2 tf01 = __half22float2(t01), tf23 = __half22float2(t23);
    float4 tq = {tf01.x, tf01.y, tf23.x, tf23.y};

    const __half* pb = phi + (size_t)b * NN * 64;
    const float* gr = gsc + n;
    const float rs = 0.2294157338705618f;  // 1/sqrt(19)

    float s[KK];
#pragma unroll
    for (int k = 0; k < KK; ++k) {
        int nd = d + OFF[k][0], nh = h + OFF[k][1], nw = w + OFF[k][2];
        nd = min(max(nd, 0), 31); nh = min(max(nh, 0), 31); nw = min(max(nw, 0), 31);
        int nn = (nd << 10) + (nh << 5) + nw;
        uint2 raw = *(const uint2*)(pb + (size_t)nn * 64 + col4 * 4);
        __half2 h01 = __builtin_bit_cast(__half2, raw.x);
        __half2 h23 = __builtin_bit_cast(__half2, raw.y);
        float2 f01 = __half22float2(h01), f23 = __half22float2(h23);
        float part = tq.x * f01.x + tq.y * f01.y + tq.z * f23.x + tq.w * f23.y;
        part += __shfl_xor(part, 1, 16);
        part += __shfl_xor(part, 2, 16);
        part += __shfl_xor(part, 4, 16);
        part += __shfl_xor(part, 8, 16);
        s[k] = fmaf(part, rs, gr[(size_t)k * NN]);  // gsc carries mask + scale
    }
    float m = s[0];
#pragma unroll
    for (int k = 1; k < KK; ++k) m = fmaxf(m, s[k]);
    float sum = 0.f;
#pragma unroll
    for (int k = 0; k < KK; ++k) { s[k] = __expf(s[k] - m); sum += s[k]; }
    float inv = 1.f / sum;
#pragma unroll
    for (int kk2 = 0; kk2 < 2; ++kk2) {
        int k = kk2 * 16 + col4;
        if (k < KK) wgt[((size_t)b * KK + k) * NN + n] = s[k] * inv;
    }
}

// ---------------- Kernel 4: propagation, wgt hoisted across channels -------
// thread = (b, n, c-group of 7); loads 19 weights + 19 neighbor idx ONCE,
// loops 7 channels. 768 blocks -> 12 waves/CU. (round-12/13 measured-good)
__global__ __launch_bounds__(256) void prop_kernel(
    const float* __restrict__ cin, const float* __restrict__ wgt,
    float* __restrict__ cout)
{
    int gid = blockIdx.x * 256 + threadIdx.x;   // B*N*3 threads
    int n = gid & (NN - 1);
    int rest = gid >> 15;                       // 0..5
    int b = rest / 3, cg = rest % 3;
    int c0 = cg * 7;
    int d = n >> 10, h = (n >> 5) & 31, w = n & 31;

    const float* wb = wgt + (size_t)b * KK * NN + n;
    int nidx[KK];
    float wv[KK];
#pragma unroll
    for (int k = 0; k < KK; ++k) {
        int nd = d + OFF[k][0], nh = h + OFF[k][1], nw = w + OFF[k][2];
        nd = min(max(nd, 0), 31); nh = min(max(nh, 0), 31); nw = min(max(nw, 0), 31);
        nidx[k] = (nd << 10) + (nh << 5) + nw;
        wv[k] = wb[(size_t)k * NN];
    }

    const float* cb = cin + ((size_t)b * CC + c0) * NN;
    float* co = cout + ((size_t)b * CC + c0) * NN + n;
#pragma unroll
    for (int cc = 0; cc < 7; ++cc) {
        float acc = 0.f;
#pragma unroll
        for (int k = 0; k < KK; ++k)
            acc = fmaf(wv[k], cb[nidx[k]], acc);
        co[(size_t)cc * NN] = acc;
        cb += NN;
    }
}

extern "C" void kernel_launch(void* const* d_in, const int* in_sizes, int n_in,
                              void* d_out, int out_size, void* d_ws, size_t ws_size,
                              hipStream_t stream) {
    const float* cam = (const float*)d_in[0];
    const float* f   = (const float*)d_in[1];
    const float* thw = (const float*)d_in[2];
    const float* thb = (const float*)d_in[3];
    const float* phw = (const float*)d_in[4];
    const float* phb = (const float*)d_in[5];
    const float* gtw = (const float*)d_in[6];
    const float* gtb = (const float*)d_in[7];
    const float* gpw = (const float*)d_in[8];
    const float* gpb = (const float*)d_in[9];

    float*  ws    = (float*)d_ws;
    __half* theta = (__half*)ws;                                  // [B,N,64] f16
    __half* phi   = theta + (size_t)BB * NN * 64;                 // [B,N,64] f16
    float*  wgt   = (float*)(phi + (size_t)BB * NN * 64);         // [B,19,N] f32
    float*  gsc   = wgt + (size_t)BB * KK * NN;                   // [19,N] k-major
    float*  cam1  = gsc + (size_t)KK * NN;                        // [B,21,N]
    uint4*  whi   = (uint4*)(cam1 + (size_t)BB * CC * NN);        // 4096 uint4
    float*  Tg    = (float*)(whi + 4096);                         // 9409 floats

    tbl_kernel<<<26, 256, 0, stream>>>(gtw, gtb, gpw, gpb, thw, phw, Tg, whi);
    proj_kernel<<<512, 512, 0, stream>>>(f, whi, thb, phb, theta, phi);
    gsc_kernel<<<NN / 256, 256, 0, stream>>>(Tg, gsc);
    score_kernel<<<BB * NN / 16, 256, 0, stream>>>(theta, phi, gsc, wgt);
    prop_kernel<<<BB * NN * 3 / 256, 256, 0, stream>>>(cam, wgt, cam1);
    prop_kernel<<<BB * NN * 3 / 256, 256, 0, stream>>>(cam1, wgt, (float*)d_out);
}

// Round 19
// 65.168 us; speedup vs baseline: 1.9711x; 1.0049x over previous
//
#include <hip/hip_runtime.h>
#include <hip/hip_bf16.h>
#include <hip/hip_fp16.h>

#define DD 32
#define HH 32
#define WW 32
#define NN 32768
#define BB 2
#define CF 256
#define CC 21
#define FD 64
#define KK 19

typedef __attribute__((ext_vector_type(8))) short bf16x8;
typedef __attribute__((ext_vector_type(4))) float f32x4;

// 19 stencil offsets with |dx|+|dy|+|dz| <= 2 (order irrelevant: softmax+sum over k)
__device__ const int OFF[19][3] = {
    {-1,-1, 0}, {-1, 0,-1}, {-1, 0, 0}, {-1, 0, 1}, {-1, 1, 0},
    { 0,-1,-1}, { 0,-1, 0}, { 0,-1, 1}, { 0, 0,-1}, { 0, 0, 0},
    { 0, 0, 1}, { 0, 1,-1}, { 0, 1, 0}, { 0, 1, 1},
    { 1,-1, 0}, { 1, 0,-1}, { 1, 0, 0}, { 1, 0, 1}, { 1, 1, 0}
};

__device__ __forceinline__ unsigned short f2bf(float x) {
    unsigned u = __float_as_uint(x);
    u += 0x7FFFu + ((u >> 16) & 1u);       // round-to-nearest-even
    return (unsigned short)(u >> 16);
}

// ---------------- Kernel A: geo tables + weight prepack -------------------
// pe separable -> geo dot = 9 pairwise 32x32 tables + U/V vectors + S0.
// blocks 0-8: one T table each; block 9: U/V/S0; blocks 10-25: proj wprep
// (flat [k/8][col] fragment layout, plain RNE bf16).
__global__ __launch_bounds__(256) void tbl_kernel(
    const float* __restrict__ gtw, const float* __restrict__ gtb,
    const float* __restrict__ gpw, const float* __restrict__ gpb,
    const float* __restrict__ thw, const float* __restrict__ phw,
    float* __restrict__ Tg, uint4* __restrict__ whi)
{
    int blk = blockIdx.x, tid = threadIdx.x;
    if (blk >= 10) {
        int gid = (blk - 10) * 256 + tid;
        int col = gid & 127;
        int g8 = gid >> 7;                          // k/8, 0..31
        const float* src = (col < 64) ? (thw + col) : (phw + (col - 64));
        int kbase = g8 * 8;
        unsigned hi4[4];
#pragma unroll
        for (int e2 = 0; e2 < 4; ++e2) {
            float va = src[(kbase + 2 * e2) * 64];
            float vb = src[(kbase + 2 * e2 + 1) * 64];
            hi4[e2] = (unsigned)f2bf(va) | ((unsigned)f2bf(vb) << 16);
        }
        whi[g8 * 128 + col] = make_uint4(hi4[0], hi4[1], hi4[2], hi4[3]);
        return;
    }

    __shared__ float pe_s[32][16];        // [coord][q]: sin/cos table, once
    for (int i = tid; i < 512; i += 256) {
        int c = i >> 4, q = i & 15;
        int ii = q >> 1;
        float div = expf(-9.210340371976184f * (float)ii * 0.125f);  // (1e-4)^(ii/8)
        float ang = (float)c * div;
        pe_s[c][q] = (q & 1) ? cosf(ang) : sinf(ang);
    }
    __syncthreads();

    __shared__ float panels[6][32][65];   // [65]: conflict-free column reads
    int npan = (blk == 9) ? 6 : 2;
#pragma unroll 1
    for (int pp = 0; pp < npan; ++pp) {
        int axis, isP;
        if (blk == 9) { axis = pp % 3; isP = pp / 3; }
        else          { axis = (pp == 0) ? (blk / 3) : (blk % 3); isP = pp; }
        const float* W = isP ? gpw : gtw;
#pragma unroll
        for (int e = 0; e < 8; ++e) {
            int idx = e * 256 + tid;       // 2048 entries
            int c = idx >> 6, j = idx & 63;
            float acc = 0.f;
#pragma unroll
            for (int q = 0; q < 16; ++q)
                acc = fmaf(pe_s[c][q], W[(axis * 16 + q) * 64 + j], acc);
            panels[pp][c][j] = acc;
        }
    }
    __syncthreads();

    if (blk < 9) {
        bool tr = (blk == 6) || (blk == 7);   // T_wd, T_wh transposed
#pragma unroll
        for (int e = 0; e < 4; ++e) {
            int idx = e * 256 + tid;          // 1024 entries
            int x = idx >> 5, y = idx & 31;
            float s = 0.f;
#pragma unroll
            for (int j = 0; j < 64; ++j)
                s = fmaf(panels[0][x][j], panels[1][y][j], s);
            Tg[blk * 1024 + (tr ? (y * 32 + x) : (x * 32 + y))] = s;
        }
    } else {
        if (tid < 96) {
            int ax = tid >> 5, c = tid & 31;
            float s = 0.f;
#pragma unroll
            for (int j = 0; j < 64; ++j) s = fmaf(panels[ax][c][j], gpb[j], s);
            Tg[9216 + ax * 32 + c] = s;
        } else if (tid < 192) {
            int t2 = tid - 96;
            int ax = t2 >> 5, c = t2 & 31;
            float s = 0.f;
#pragma unroll
            for (int j = 0; j < 64; ++j) s = fmaf(gtb[j], panels[3 + ax][c][j], s);
            Tg[9312 + ax * 32 + c] = s;
        } else if (tid == 192) {
            float s = 0.f;
#pragma unroll
            for (int j = 0; j < 64; ++j) s = fmaf(gtb[j], gpb[j], s);
            Tg[9408] = s;
        }
    }
}

// ---------------- Kernel 1: projection GEMM, pure bf16 MFMA ----------------
// 128x128 tile, 8 waves (each 32x64 quadrant), BK=64, 4 K-steps.
// grid 512, LDS 32 KB -> 2 blocks/CU, 16 waves/CU.
// Single MFMA per fragment pair; slot = kb ^ (row&7). theta/phi f16 out.
__global__ __launch_bounds__(512) void proj_kernel(
    const float* __restrict__ f, const uint4* __restrict__ whi,
    const float* __restrict__ thb, const float* __restrict__ phb,
    __half* __restrict__ theta, __half* __restrict__ phi)
{
    __shared__ __align__(16) unsigned short Ahi[128][8][8];   // 16 KB
    __shared__ __align__(16) unsigned short Bhi[128][8][8];   // 16 KB

    int tid = threadIdx.x;
    int b = blockIdx.x >> 8;                  // 256 tiles per batch
    int n0 = (blockIdx.x & 255) * 128;
    int wv = tid >> 6, lane = tid & 63;
    int wr = (wv & 3) * 32, wc = (wv >> 2) * 64;
    int fr = lane & 15, kb_r = lane >> 4;

    int srow = tid & 127;                     // staging row (A) / col (B)
    int kb0 = (tid >> 7) * 2;                 // staging kb base: 0,2,4,6

    const float* fb = f + (size_t)b * CF * NN + n0;

    f32x4 acc[2][4];
#pragma unroll
    for (int mi = 0; mi < 2; ++mi)
#pragma unroll
        for (int ni = 0; ni < 4; ++ni) acc[mi][ni] = (f32x4){0.f, 0.f, 0.f, 0.f};

#pragma unroll 1
    for (int k0 = 0; k0 < CF; k0 += 64) {
        // ---- stage A: 128 rows x 64 k; thread owns n=srow, kb=kb0..kb0+1
#pragma unroll
        for (int i = 0; i < 2; ++i) {
            int kb = kb0 + i;
            const float* src = fb + (size_t)(k0 + kb * 8) * NN + srow;
            unsigned hi4[4];
#pragma unroll
            for (int e2 = 0; e2 < 4; ++e2) {
                float va = src[(size_t)(2 * e2) * NN];
                float vb = src[(size_t)(2 * e2 + 1) * NN];
                hi4[e2] = (unsigned)f2bf(va) | ((unsigned)f2bf(vb) << 16);
            }
            int slot = kb ^ (srow & 7);
            *(uint4*)&Ahi[srow][slot][0] = make_uint4(hi4[0], hi4[1], hi4[2], hi4[3]);
        }
        // ---- stage B: prepacked fragments, straight 16B copies
        {
            const uint4* wh = whi + (size_t)(k0 >> 3) * 128;   // flat [k/8][col]
#pragma unroll
            for (int i = 0; i < 2; ++i) {
                int kb = kb0 + i;
                uint4 hh = wh[kb * 128 + srow];
                int slot = kb ^ (srow & 7);
                *(uint4*)&Bhi[srow][slot][0] = hh;
            }
        }
        __syncthreads();
        // ---- two K=32 MFMA chunks
#pragma unroll
        for (int c = 0; c < 2; ++c) {
            bf16x8 ah[2], bh[4];
            int kb_c = c * 4 + kb_r;
#pragma unroll
            for (int mi = 0; mi < 2; ++mi) {
                int r = wr + mi * 16 + fr;
                int slot = kb_c ^ (r & 7);
                ah[mi] = *(const bf16x8*)&Ahi[r][slot][0];
            }
#pragma unroll
            for (int ni = 0; ni < 4; ++ni) {
                int col = wc + ni * 16 + fr;
                int slot = kb_c ^ (col & 7);
                bh[ni] = *(const bf16x8*)&Bhi[col][slot][0];
            }
#pragma unroll
            for (int mi = 0; mi < 2; ++mi)
#pragma unroll
                for (int ni = 0; ni < 4; ++ni)
                    acc[mi][ni] = __builtin_amdgcn_mfma_f32_16x16x32_bf16(ah[mi], bh[ni], acc[mi][ni], 0, 0, 0);
        }
        __syncthreads();
    }

    // ---- epilogue: C/D col=lane&15, row=(lane>>4)*4+r; branch wave-uniform
#pragma unroll
    for (int ni = 0; ni < 4; ++ni) {
        int j = wc + ni * 16 + fr;
        float bj = (j < 64) ? thb[j] : phb[j - 64];
        __half* outp = (j < 64) ? (theta + (size_t)b * NN * 64 + j)
                                : (phi + (size_t)b * NN * 64 + (j - 64));
#pragma unroll
        for (int mi = 0; mi < 2; ++mi) {
            int nbase = n0 + wr + mi * 16 + kb_r * 4;
#pragma unroll
            for (int r = 0; r < 4; ++r)
                outp[(size_t)(nbase + r) * 64] = __float2half(acc[mi][ni][r] + bj);
        }
    }
}

// ---------------- Kernel 2: geo scores from tables ------------------------
__global__ __launch_bounds__(256) void gsc_kernel(
    const float* __restrict__ Tg, float* __restrict__ gsc)
{
    __shared__ float Ts[9 * 1024];
    __shared__ float UVs[193];
    int tid = threadIdx.x;
#pragma unroll
    for (int i = 0; i < 9; ++i) {
        int idx = i * 1024 + tid;
        Ts[idx] = Tg[idx];
        Ts[idx + 256] = Tg[idx + 256];
        Ts[idx + 512] = Tg[idx + 512];
        Ts[idx + 768] = Tg[idx + 768];
    }
    if (tid < 193) UVs[tid] = Tg[9216 + tid];
    __syncthreads();

    int n = blockIdx.x * 256 + tid;
    int d = n >> 10, h = (n >> 5) & 31, w = n & 31;
    float Un = UVs[d] + UVs[32 + h] + UVs[64 + w] + UVs[192];
    const float rs = 0.2294157338705618f;  // 1/sqrt(19)

#pragma unroll
    for (int k = 0; k < KK; ++k) {
        int nd = d + OFF[k][0], nh = h + OFF[k][1], nw = w + OFF[k][2];
        bool valid = ((unsigned)nd < 32u) && ((unsigned)nh < 32u) && ((unsigned)nw < 32u);
        int ndc = min(max(nd, 0), 31), nhc = min(max(nh, 0), 31), nwc = min(max(nw, 0), 31);
        float g = Ts[0 * 1024 + d * 32 + ndc] + Ts[1 * 1024 + d * 32 + nhc]
                + Ts[2 * 1024 + d * 32 + nwc] + Ts[3 * 1024 + h * 32 + ndc]
                + Ts[4 * 1024 + h * 32 + nhc] + Ts[5 * 1024 + h * 32 + nwc]
                + Ts[6 * 1024 + ndc * 32 + w] + Ts[7 * 1024 + nhc * 32 + w]
                + Ts[8 * 1024 + w * 32 + nwc]
                + Un + UVs[96 + ndc] + UVs[128 + nhc] + UVs[160 + nwc];
        gsc[(size_t)k * NN + n] = valid ? g * rs : -INFINITY;
    }
}

// ---------------- Kernel 3: scores + masked softmax ----------------
__global__ __launch_bounds__(256) void score_kernel(
    const __half* __restrict__ theta, const __half* __restrict__ phi,
    const float* __restrict__ gsc, float* __restrict__ wgt)
{
    int tid = threadIdx.x;
    int lane = tid & 63;
    int wv = tid >> 6;
    int sub = lane >> 4;
    int col4 = lane & 15;
    int gn = blockIdx.x * 16 + wv * 4 + sub;    // over B*N
    int b = gn >> 15;
    int n = gn & (NN - 1);
    int d = n >> 10, h = (n >> 5) & 31, w = n & 31;

    uint2 traw = *(const uint2*)(theta + (size_t)gn * 64 + col4 * 4);
    __half2 t01 = __builtin_bit_cast(__half2, traw.x);
    __half2 t23 = __builtin_bit_cast(__half2, traw.y);
    float2 tf01 = __half22float2(t01), tf23 = __half22float2(t23);
    float4 tq = {tf01.x, tf01.y, tf23.x, tf23.y};

    const __half* pb = phi + (size_t)b * NN * 64;
    const float* gr = gsc + n;
    const float rs = 0.2294157338705618f;  // 1/sqrt(19)

    float s[KK];
#pragma unroll
    for (int k = 0; k < KK; ++k) {
        int nd = d + OFF[k][0], nh = h + OFF[k][1], nw = w + OFF[k][2];
        nd = min(max(nd, 0), 31); nh = min(max(nh, 0), 31); nw = min(max(nw, 0), 31);
        int nn = (nd << 10) + (nh << 5) + nw;
        uint2 raw = *(const uint2*)(pb + (size_t)nn * 64 + col4 * 4);
        __half2 h01 = __builtin_bit_cast(__half2, raw.x);
        __half2 h23 = __builtin_bit_cast(__half2, raw.y);
        float2 f01 = __half22float2(h01), f23 = __half22float2(h23);
        float part = tq.x * f01.x + tq.y * f01.y + tq.z * f23.x + tq.w * f23.y;
        part += __shfl_xor(part, 1, 16);
        part += __shfl_xor(part, 2, 16);
        part += __shfl_xor(part, 4, 16);
        part += __shfl_xor(part, 8, 16);
        s[k] = fmaf(part, rs, gr[(size_t)k * NN]);  // gsc carries mask + scale
    }
    float m = s[0];
#pragma unroll
    for (int k = 1; k < KK; ++k) m = fmaxf(m, s[k]);
    float sum = 0.f;
#pragma unroll
    for (int k = 0; k < KK; ++k) { s[k] = __expf(s[k] - m); sum += s[k]; }
    float inv = 1.f / sum;
#pragma unroll
    for (int kk2 = 0; kk2 < 2; ++kk2) {
        int k = kk2 * 16 + col4;
        if (k < KK) wgt[((size_t)b * KK + k) * NN + n] = s[k] * inv;
    }
}

// ---------------- Kernel 4: propagation, wgt hoisted across channels -------
// thread = (b, n, c-group of 7); 19 weights + 19 neighbor idx loaded ONCE,
// loops 7 channels. 768 blocks -> 12 waves/CU. Templated on IO precision:
// pass 1 f32->f16 (cam1 intermediate), pass 2 f16->f32 (halves pass-2
// gather traffic + intermediate HBM round trip; error ~5e-4 << threshold).
template <typename TIN, typename TOUT>
__global__ __launch_bounds__(256) void prop_kernel(
    const TIN* __restrict__ cin, const float* __restrict__ wgt,
    TOUT* __restrict__ cout)
{
    int gid = blockIdx.x * 256 + threadIdx.x;   // B*N*3 threads
    int n = gid & (NN - 1);
    int rest = gid >> 15;                       // 0..5
    int b = rest / 3, cg = rest % 3;
    int c0 = cg * 7;
    int d = n >> 10, h = (n >> 5) & 31, w = n & 31;

    const float* wb = wgt + (size_t)b * KK * NN + n;
    int nidx[KK];
    float wv[KK];
#pragma unroll
    for (int k = 0; k < KK; ++k) {
        int nd = d + OFF[k][0], nh = h + OFF[k][1], nw = w + OFF[k][2];
        nd = min(max(nd, 0), 31); nh = min(max(nh, 0), 31); nw = min(max(nw, 0), 31);
        nidx[k] = (nd << 10) + (nh << 5) + nw;
        wv[k] = wb[(size_t)k * NN];
    }

    const TIN* cb = cin + ((size_t)b * CC + c0) * NN;
    TOUT* co = cout + ((size_t)b * CC + c0) * NN + n;
#pragma unroll
    for (int cc = 0; cc < 7; ++cc) {
        float acc = 0.f;
#pragma unroll
        for (int k = 0; k < KK; ++k)
            acc = fmaf(wv[k], (float)cb[nidx[k]], acc);
        co[(size_t)cc * NN] = (TOUT)acc;
        cb += NN;
    }
}

extern "C" void kernel_launch(void* const* d_in, const int* in_sizes, int n_in,
                              void* d_out, int out_size, void* d_ws, size_t ws_size,
                              hipStream_t stream) {
    const float* cam = (const float*)d_in[0];
    const float* f   = (const float*)d_in[1];
    const float* thw = (const float*)d_in[2];
    const float* thb = (const float*)d_in[3];
    const float* phw = (const float*)d_in[4];
    const float* phb = (const float*)d_in[5];
    const float* gtw = (const float*)d_in[6];
    const float* gtb = (const float*)d_in[7];
    const float* gpw = (const float*)d_in[8];
    const float* gpb = (const float*)d_in[9];

    float*  ws    = (float*)d_ws;
    __half* theta = (__half*)ws;                                  // [B,N,64] f16
    __half* phi   = theta + (size_t)BB * NN * 64;                 // [B,N,64] f16
    float*  wgt   = (float*)(phi + (size_t)BB * NN * 64);         // [B,19,N] f32
    float*  gsc   = wgt + (size_t)BB * KK * NN;                   // [19,N] k-major
    __half* cam1h = (__half*)(gsc + (size_t)KK * NN);             // [B,21,N] f16
    uint4*  whi   = (uint4*)((char*)cam1h + (size_t)BB * CC * NN * 2); // 4096 uint4
    float*  Tg    = (float*)(whi + 4096);                         // 9409 floats

    tbl_kernel<<<26, 256, 0, stream>>>(gtw, gtb, gpw, gpb, thw, phw, Tg, whi);
    proj_kernel<<<512, 512, 0, stream>>>(f, whi, thb, phb, theta, phi);
    gsc_kernel<<<NN / 256, 256, 0, stream>>>(Tg, gsc);
    score_kernel<<<BB * NN / 16, 256, 0, stream>>>(theta, phi, gsc, wgt);
    prop_kernel<float, __half><<<BB * NN * 3 / 256, 256, 0, stream>>>(cam, wgt, cam1h);
    prop_kernel<__half, float><<<BB * NN * 3 / 256, 256, 0, stream>>>(cam1h, wgt, (float*)d_out);
}